// Round 1
// baseline (363.162 us; speedup 1.0000x reference)
//
#include <hip/hip_runtime.h>
#include <hip/hip_bf16.h>

// DirectionalConv mode='down': out[b,co,d,h,w] =
//   sum_{ci,i,k} x[b,ci, d+i-2, h+i-2, w+k-2] * W[co,ci,i,0,k] + bias[co]
// x: (2,32,48,64,128) f32, W: (32,32,5,1,5), out: (2,32,48,68,128) f32.

#define NB   2
#define CIN  32
#define COUT 32
#define DD   48
#define HH   64
#define WW   128
#define DO   48
#define HO   68
#define WO   128
#define K0   5
#define K2   5

#define RS   168            // row stride (ushort) for xs[col][r], 16B-aligned rows
#define NROW 160            // 5 d-taps * 32 ci
#define NCOL 132            // w = -2 .. 129  (col = w+2)

typedef __attribute__((ext_vector_type(8))) short bf16x8;
typedef __attribute__((ext_vector_type(4))) float f32x4;

__device__ __forceinline__ unsigned short f32_to_bf16(float v) {
    unsigned int u; __builtin_memcpy(&u, &v, 4);
    u += 0x7FFFu + ((u >> 16) & 1u);        // RNE
    return (unsigned short)(u >> 16);
}

// Pre-pack weights into MFMA A-fragment order:
// frag f = (kk*5 + c)*2 + mt ; lane l ; 8 bf16 = W[mt*16+(l&15)][ci=(l>>4)*8+j][i=c][kk]
__global__ void prep_weights_kernel(const float* __restrict__ wgt,
                                    unsigned int* __restrict__ ws) {
    int s = blockIdx.x * 256 + threadIdx.x;     // 50 frags * 64 lanes = 3200 slots
    if (s >= 3200) return;
    int f = s >> 6, l = s & 63;
    int mt = f & 1, kkc = f >> 1;
    int kk = kkc / 5, c = kkc - kk * 5;
    int co = mt * 16 + (l & 15);
    int cib = (l >> 4) * 8;
    unsigned int u[4];
#pragma unroll
    for (int jp = 0; jp < 4; ++jp) {
        // weight flat index: co*800 + ci*25 + i*5 + kk
        float v0 = wgt[co * 800 + (cib + 2 * jp + 0) * 25 + c * 5 + kk];
        float v1 = wgt[co * 800 + (cib + 2 * jp + 1) * 25 + c * 5 + kk];
        u[jp] = (unsigned int)f32_to_bf16(v0) | ((unsigned int)f32_to_bf16(v1) << 16);
    }
    uint4 pack; pack.x = u[0]; pack.y = u[1]; pack.z = u[2]; pack.w = u[3];
    reinterpret_cast<uint4*>(ws)[s] = pack;
}

__global__ void __launch_bounds__(256)
dconv_kernel(const float* __restrict__ x,
             const float* __restrict__ bias,
             const bf16x8* __restrict__ wsf,   // packed A fragments
             float* __restrict__ out) {
    __shared__ __align__(16) unsigned short xs[NCOL * RS];

    const int tid = threadIdx.x;
    const int h = blockIdx.x;       // 0..67
    const int d = blockIdx.y;       // 0..47
    const int b = blockIdx.z;       // 0..1

    // ---- stage x slab (transposed, bf16): xs[col][r], r = i*32+ci ----
    // 160 rows * 132 cols = 21120 elems; r fastest across lanes -> contiguous LDS writes
    for (int it = 0; it < 83; ++it) {
        int e = it * 256 + tid;
        if (e < NROW * NCOL) {
            unsigned int eu = (unsigned int)e;
            int col = (int)(eu / NROW);
            int r   = (int)(eu - (unsigned int)col * NROW);
            int i = r >> 5, ci = r & 31;
            int dz = d + i - 2, hz = h + i - 2, wz = col - 2;
            float v = 0.0f;
            if ((unsigned)dz < (unsigned)DD && (unsigned)hz < (unsigned)HH &&
                (unsigned)wz < (unsigned)WW) {
                v = x[(((b * CIN + ci) * DD + dz) * HH + hz) * WW + wz];
            }
            xs[col * RS + r] = f32_to_bf16(v);
        }
    }
    __syncthreads();

    // ---- MFMA: out tile 32co x 128w ; wave wv owns w in [wv*32, wv*32+32) ----
    const int l  = tid & 63;
    const int wv = tid >> 6;
    const int lr = l & 15;
    const int lg = l >> 4;
    const int wbase = wv * 32;

    f32x4 acc[2][2] = {};

#pragma unroll
    for (int kk = 0; kk < K2; ++kk) {
#pragma unroll
        for (int c = 0; c < K0; ++c) {
            int f0 = ((kk * 5 + c) * 2) * 64 + l;
            bf16x8 a0 = wsf[f0];
            bf16x8 a1 = wsf[f0 + 64];
#pragma unroll
            for (int nt = 0; nt < 2; ++nt) {
                const bf16x8* bp = reinterpret_cast<const bf16x8*>(
                    &xs[(wbase + nt * 16 + lr + kk) * RS + c * 32 + lg * 8]);
                bf16x8 bv = *bp;
                acc[0][nt] = __builtin_amdgcn_mfma_f32_16x16x32_bf16(a0, bv, acc[0][nt], 0, 0, 0);
                acc[1][nt] = __builtin_amdgcn_mfma_f32_16x16x32_bf16(a1, bv, acc[1][nt], 0, 0, 0);
            }
        }
    }

    // ---- epilogue: D[row][col]: col=lane&15, row=(lane>>4)*4+reg ----
#pragma unroll
    for (int mt = 0; mt < 2; ++mt) {
#pragma unroll
        for (int nt = 0; nt < 2; ++nt) {
#pragma unroll
            for (int rg = 0; rg < 4; ++rg) {
                int co = mt * 16 + lg * 4 + rg;
                int w  = wbase + nt * 16 + lr;
                out[(((b * COUT + co) * DO + d) * HO + h) * WO + w] =
                    acc[mt][nt][rg] + bias[co];
            }
        }
    }
}

extern "C" void kernel_launch(void* const* d_in, const int* in_sizes, int n_in,
                              void* d_out, int out_size, void* d_ws, size_t ws_size,
                              hipStream_t stream) {
    const float* x    = (const float*)d_in[0];
    const float* wgt  = (const float*)d_in[1];
    const float* bias = (const float*)d_in[2];
    float* out = (float*)d_out;
    unsigned int* ws = (unsigned int*)d_ws;

    // pack weights into A-fragment layout (51200 B in d_ws)
    prep_weights_kernel<<<13, 256, 0, stream>>>(wgt, ws);

    dim3 grid(HO, DO, NB);
    dconv_kernel<<<grid, 256, 0, stream>>>(x, bias, (const bf16x8*)ws, out);
}

// Round 2
// 121.644 us; speedup vs baseline: 2.9854x; 2.9854x over previous
//
#include <hip/hip_runtime.h>
#include <hip/hip_bf16.h>

// DirectionalConv mode='down': out[b,co,d,h,w] =
//   sum_{ci,i,k} x[b,ci, d+i-2, h+i-2, w+k-2] * W[co,ci,i,0,k] + bias[co]
// x: (2,32,48,64,128) f32, W: (32,32,5,1,5), out: (2,32,48,68,128) f32.

#define NB   2
#define CIN  32
#define COUT 32
#define DD   48
#define HH   64
#define WW   128
#define DOUT 48
#define HO   68
#define WO   128

#define RS   192            // ushorts per col (24 chunks of 8B*? -> room for XOR swizzle)
#define NROW 160            // 5 d-taps * 32 ci
#define NCOL 132            // col = w + 2, w in [-2, 130); cols 0,1,130,131 always zero

typedef __attribute__((ext_vector_type(8))) short bf16x8;
typedef __attribute__((ext_vector_type(4))) float f32x4;

__device__ __forceinline__ unsigned short f32_to_bf16(float v) {
    unsigned int u; __builtin_memcpy(&u, &v, 4);
    u += 0x7FFFu + ((u >> 16) & 1u);        // RNE
    return (unsigned short)(u >> 16);
}

// swizzled LDS index: xs[col][roff], roff XOR'd on bits [3:5] by (col>>2)&7.
// Applied identically on write and read (both-sides-or-neither).
__device__ __forceinline__ int xs_idx(int col, int roff) {
    return col * RS + (roff ^ (((col >> 2) & 7) << 3));
}

// Pre-pack weights into MFMA A-fragment order:
// frag f = (c*5 + kk)*2 + mt ; lane l ; 8 bf16 = W[mt*16+(l&15)][ci=(l>>4)*8+j][i=c][kk]
__global__ void prep_weights_kernel(const float* __restrict__ wgt,
                                    unsigned int* __restrict__ ws) {
    int s = blockIdx.x * 256 + threadIdx.x;     // 50 frags * 64 lanes = 3200 slots
    if (s >= 3200) return;
    int f = s >> 6, l = s & 63;
    int mt = f & 1, ckk = f >> 1;
    int c = ckk / 5, kk = ckk - c * 5;
    int co = mt * 16 + (l & 15);
    int cib = (l >> 4) * 8;
    unsigned int u[4];
#pragma unroll
    for (int jp = 0; jp < 4; ++jp) {
        // weight flat index: co*800 + ci*25 + i*5 + kk
        float v0 = wgt[co * 800 + (cib + 2 * jp + 0) * 25 + c * 5 + kk];
        float v1 = wgt[co * 800 + (cib + 2 * jp + 1) * 25 + c * 5 + kk];
        u[jp] = (unsigned int)f32_to_bf16(v0) | ((unsigned int)f32_to_bf16(v1) << 16);
    }
    uint4 pack; pack.x = u[0]; pack.y = u[1]; pack.z = u[2]; pack.w = u[3];
    reinterpret_cast<uint4*>(ws)[s] = pack;
}

__global__ void __launch_bounds__(256)
dconv_kernel(const float* __restrict__ x,
             const float* __restrict__ bias,
             const bf16x8* __restrict__ wsf,   // packed A fragments
             float* __restrict__ out) {
    __shared__ __align__(16) unsigned short xs[NCOL * RS];

    const int tid = threadIdx.x;
    const int h = blockIdx.x;       // 0..67
    const int d = blockIdx.y;       // 0..47
    const int b = blockIdx.z;       // 0..1

    // ---- zero the 4 always-zero halo cols (0,1,130,131), full RS rows ----
    // 4 cols * 192 ushorts = 96 chunks of 8 ushorts (16B)
    if (tid < 96) {
        int colIdx = tid / 24;              // 0..3
        int ch     = tid - colIdx * 24;     // 0..23
        int col    = (colIdx < 2) ? colIdx : 128 + colIdx;
        f32x4 z = {};
        *reinterpret_cast<f32x4*>(&xs[col * RS + ch * 8]) = z;
    }

    // ---- stage interior cols 2..129 (wz 0..127), coalesced float4 loads ----
    // 10 iterations; per iter: 16 rows (one i-tap half) x 128 w.
    // thread: wc = tid&31 -> w = 4*wc..4*wc+3 ; rpair = tid>>5 -> rows r, r+1.
    {
        const int wc = tid & 31;
        const int rp = tid >> 5;            // 0..7
#pragma unroll
        for (int it = 0; it < 10; ++it) {
            int i  = it >> 1;                           // d-tap, uniform per iter
            int ci = ((it & 1) << 4) + (rp << 1);       // even ci; pair covers ci, ci+1
            int dz = d + i - 2, hz = h + i - 2;
            float4 v0 = {0.f, 0.f, 0.f, 0.f};
            float4 v1 = {0.f, 0.f, 0.f, 0.f};
            if (((unsigned)dz < (unsigned)DD) && ((unsigned)hz < (unsigned)HH)) {
                const float* base = &x[((((size_t)b * CIN + ci) * DD + dz) * HH + hz) * WW + wc * 4];
                v0 = *reinterpret_cast<const float4*>(base);
                v1 = *reinterpret_cast<const float4*>(base + (size_t)DD * HH * WW);
            }
            int r = i * 32 + ci;            // even; pair (r, r+1) packs into one dword
            const float* p0 = &v0.x;
            const float* p1 = &v1.x;
#pragma unroll
            for (int j = 0; j < 4; ++j) {
                int col = wc * 4 + j + 2;
                unsigned int pk = (unsigned int)f32_to_bf16(p0[j])
                                | ((unsigned int)f32_to_bf16(p1[j]) << 16);
                *reinterpret_cast<unsigned int*>(&xs[xs_idx(col, r)]) = pk;
            }
        }
    }
    __syncthreads();

    // ---- MFMA: out tile 32co x 128w ; wave wv owns w in [wv*32, wv*32+32) ----
    const int l  = tid & 63;
    const int wv = tid >> 6;
    const int lr = l & 15;
    const int lg = l >> 4;
    const int wbase = wv * 32;

    f32x4 acc[2][2] = {};

#pragma unroll
    for (int c = 0; c < 5; ++c) {
#pragma unroll
        for (int kk = 0; kk < 5; ++kk) {
            int f0 = ((c * 5 + kk) * 2) * 64 + l;
            bf16x8 a0 = wsf[f0];
            bf16x8 a1 = wsf[f0 + 64];
#pragma unroll
            for (int nt = 0; nt < 2; ++nt) {
                int col = wbase + nt * 16 + lr + kk;     // in [0,132) always
                const bf16x8* bp = reinterpret_cast<const bf16x8*>(
                    &xs[xs_idx(col, c * 32 + lg * 8)]);
                bf16x8 bv = *bp;
                acc[0][nt] = __builtin_amdgcn_mfma_f32_16x16x32_bf16(a0, bv, acc[0][nt], 0, 0, 0);
                acc[1][nt] = __builtin_amdgcn_mfma_f32_16x16x32_bf16(a1, bv, acc[1][nt], 0, 0, 0);
            }
        }
    }

    // ---- epilogue: D[row][col]: col=lane&15, row=(lane>>4)*4+reg ----
#pragma unroll
    for (int mt = 0; mt < 2; ++mt) {
#pragma unroll
        for (int nt = 0; nt < 2; ++nt) {
#pragma unroll
            for (int rg = 0; rg < 4; ++rg) {
                int co = mt * 16 + lg * 4 + rg;
                int w  = wbase + nt * 16 + lr;
                out[((((size_t)b * COUT + co) * DOUT + d) * HO + h) * WO + w] =
                    acc[mt][nt][rg] + bias[co];
            }
        }
    }
}

extern "C" void kernel_launch(void* const* d_in, const int* in_sizes, int n_in,
                              void* d_out, int out_size, void* d_ws, size_t ws_size,
                              hipStream_t stream) {
    const float* x    = (const float*)d_in[0];
    const float* wgt  = (const float*)d_in[1];
    const float* bias = (const float*)d_in[2];
    float* out = (float*)d_out;
    unsigned int* ws = (unsigned int*)d_ws;

    // pack weights into A-fragment layout (51200 B in d_ws)
    prep_weights_kernel<<<13, 256, 0, stream>>>(wgt, ws);

    dim3 grid(HO, DOUT, NB);
    dconv_kernel<<<grid, 256, 0, stream>>>(x, bias, (const bf16x8*)ws, out);
}

// Round 3
// 90.915 us; speedup vs baseline: 3.9945x; 1.3380x over previous
//
#include <hip/hip_runtime.h>
#include <hip/hip_bf16.h>

// DirectionalConv mode='down': out[b,co,d,h,w] =
//   sum_{ci,i,k} x[b,ci, d+i-2, h+i-2, w+k-2] * W[co,ci,i,0,k] + bias[co]
// x: (2,32,48,64,128) f32, W: (32,32,5,1,5), out: (2,32,48,68,128) f32.

#define NB   2
#define CIN  32
#define COUT 32
#define DD   48
#define HH   64
#define WW   128
#define DOUT 48
#define HO   68
#define WO   128

#define RS   192            // ushorts per col = 24 16B-chunks (20 used, 4 pad)
#define NCOL 132            // col = w + 2, w in [-2, 130); cols 0,1,130,131 always zero

typedef __attribute__((ext_vector_type(8))) short bf16x8;
typedef __attribute__((ext_vector_type(4))) float f32x4;

__device__ __forceinline__ unsigned short f32_to_bf16(float v) {
    unsigned int u; __builtin_memcpy(&u, &v, 4);
    u += 0x7FFFu + ((u >> 16) & 1u);        // RNE
    return (unsigned short)(u >> 16);
}
__device__ __forceinline__ unsigned int pk_bf16(float lo, float hi) {
    return (unsigned int)f32_to_bf16(lo) | ((unsigned int)f32_to_bf16(hi) << 16);
}

// LDS geometry: logical (col, chunk t), t = r>>3, r = i*32+ci.
// phys ushort index; XOR-swizzle chunk position by s=(col>>1)&7:
//  - reads  (col=B+lr): s spans 8 values over 16 lanes -> banks at floor
//  - writes (col=2*lane+c): s spans 8 values over 64 lanes -> banks at floor
// col stride 192 ushorts = 96 dwords == 0 mod 32, so bank depends only on chunk pos.
__device__ __forceinline__ int xs_chunk(int col, int t) {
    return col * RS + ((t ^ ((col >> 1) & 7)) << 3);
}

// Pre-pack weights into MFMA A-fragment order:
// frag f = (c*5 + kk)*2 + mt ; lane l ; 8 bf16 = W[mt*16+(l&15)][ci=(l>>4)*8+j][i=c][kk]
__global__ void prep_weights_kernel(const float* __restrict__ wgt,
                                    unsigned int* __restrict__ ws) {
    int s = blockIdx.x * 256 + threadIdx.x;     // 50 frags * 64 lanes = 3200 slots
    if (s >= 3200) return;
    int f = s >> 6, l = s & 63;
    int mt = f & 1, ckk = f >> 1;
    int c = ckk / 5, kk = ckk - c * 5;
    int co = mt * 16 + (l & 15);
    int cib = (l >> 4) * 8;
    unsigned int u[4];
#pragma unroll
    for (int jp = 0; jp < 4; ++jp) {
        float v0 = wgt[co * 800 + (cib + 2 * jp + 0) * 25 + c * 5 + kk];
        float v1 = wgt[co * 800 + (cib + 2 * jp + 1) * 25 + c * 5 + kk];
        u[jp] = (unsigned int)f32_to_bf16(v0) | ((unsigned int)f32_to_bf16(v1) << 16);
    }
    uint4 pack; pack.x = u[0]; pack.y = u[1]; pack.z = u[2]; pack.w = u[3];
    reinterpret_cast<uint4*>(ws)[s] = pack;
}

__global__ void __launch_bounds__(256)
dconv_kernel(const float* __restrict__ x,
             const float* __restrict__ bias,
             const bf16x8* __restrict__ wsf,   // packed A fragments
             float* __restrict__ out) {
    __shared__ __align__(16) unsigned short xs[NCOL * RS];

    const int tid = threadIdx.x;

    // ---- diagonal-major, XCD-chunked block remap ----
    // x-plane reuse is along d-h diagonals (d,h shifts locked to the same tap).
    // e enumerates (b, diag dlt, d) with h=(d+dlt)%68; XCD-chunked so consecutive
    // e (sharing 4/5 staged planes) land on the same XCD's L2.
    int bid = blockIdx.x + HO * (blockIdx.y + DOUT * blockIdx.z);   // 0..6527
    int e   = (bid & 7) * 816 + (bid >> 3);                         // bijective, 6528=8*816
    int b   = (e >= 3264) ? 1 : 0;
    int r0  = e - b * 3264;
    int dlt = r0 / 48;                  // 0..67
    int d   = r0 - dlt * 48;            // 0..47
    int h   = d + dlt; if (h >= HO) h -= HO;

    // ---- zero the 4 always-zero halo cols (0,1,130,131), all 24 chunks ----
    if (tid < 96) {
        int colIdx = tid / 24;              // 0..3
        int ch     = tid - colIdx * 24;     // 0..23
        int col    = (colIdx < 2) ? colIdx : 128 + colIdx;
        f32x4 z = {};
        *reinterpret_cast<f32x4*>(&xs[col * RS + ch * 8]) = z;
    }

    // ---- stage interior cols 2..129: transposed, chunk-granular b128 writes ----
    // group g = i*4 + oct (20 groups); lane owns w-pair (2*lane, 2*lane+1);
    // loads 8 float2 (ci = oct*8..+7), packs, writes 2 chunks.
    {
        const int lane = tid & 63;
        const int wv   = tid >> 6;
        const int w0   = lane * 2;
        const int col0 = w0 + 2, col1 = w0 + 3;
        const size_t plane = (size_t)DD * HH * WW;
        for (int g = wv; g < 20; g += 4) {
            int i = g >> 2, oct = g & 3;
            int dz = d + i - 2, hz = h + i - 2;
            float2 v[8];
#pragma unroll
            for (int k = 0; k < 8; ++k) { v[k].x = 0.f; v[k].y = 0.f; }
            if (((unsigned)dz < (unsigned)DD) && ((unsigned)hz < (unsigned)HH)) {
                const float* base = x + ((((size_t)b * CIN + oct * 8) * DD + dz) * HH + hz) * WW + w0;
#pragma unroll
                for (int k = 0; k < 8; ++k)
                    v[k] = *reinterpret_cast<const float2*>(base + (size_t)k * plane);
            }
            uint4 c0, c1;
            c0.x = pk_bf16(v[0].x, v[1].x); c0.y = pk_bf16(v[2].x, v[3].x);
            c0.z = pk_bf16(v[4].x, v[5].x); c0.w = pk_bf16(v[6].x, v[7].x);
            c1.x = pk_bf16(v[0].y, v[1].y); c1.y = pk_bf16(v[2].y, v[3].y);
            c1.z = pk_bf16(v[4].y, v[5].y); c1.w = pk_bf16(v[6].y, v[7].y);
            *reinterpret_cast<uint4*>(&xs[xs_chunk(col0, g)]) = c0;
            *reinterpret_cast<uint4*>(&xs[xs_chunk(col1, g)]) = c1;
        }
    }
    __syncthreads();

    // ---- MFMA: out tile 32co x 128w ; wave wv owns w in [wv*32, wv*32+32) ----
    const int l  = tid & 63;
    const int wv = tid >> 6;
    const int lr = l & 15;
    const int lg = l >> 4;
    const int wbase = wv * 32;

    f32x4 acc[2][2] = {};

#pragma unroll
    for (int c = 0; c < 5; ++c) {
#pragma unroll
        for (int kk = 0; kk < 5; ++kk) {
            int f0 = ((c * 5 + kk) * 2) * 64 + l;
            bf16x8 a0 = wsf[f0];
            bf16x8 a1 = wsf[f0 + 64];
#pragma unroll
            for (int nt = 0; nt < 2; ++nt) {
                int col = wbase + nt * 16 + lr + kk;     // in [0,132) always
                bf16x8 bv = *reinterpret_cast<const bf16x8*>(
                    &xs[xs_chunk(col, c * 4 + lg)]);
                acc[0][nt] = __builtin_amdgcn_mfma_f32_16x16x32_bf16(a0, bv, acc[0][nt], 0, 0, 0);
                acc[1][nt] = __builtin_amdgcn_mfma_f32_16x16x32_bf16(a1, bv, acc[1][nt], 0, 0, 0);
            }
        }
    }

    // ---- epilogue: D[row][col]: col=lane&15, row=(lane>>4)*4+reg ----
#pragma unroll
    for (int mt = 0; mt < 2; ++mt) {
#pragma unroll
        for (int nt = 0; nt < 2; ++nt) {
#pragma unroll
            for (int rg = 0; rg < 4; ++rg) {
                int co = mt * 16 + lg * 4 + rg;
                int w  = wbase + nt * 16 + lr;
                out[((((size_t)b * COUT + co) * DOUT + d) * HO + h) * WO + w] =
                    acc[mt][nt][rg] + bias[co];
            }
        }
    }
}

extern "C" void kernel_launch(void* const* d_in, const int* in_sizes, int n_in,
                              void* d_out, int out_size, void* d_ws, size_t ws_size,
                              hipStream_t stream) {
    const float* x    = (const float*)d_in[0];
    const float* wgt  = (const float*)d_in[1];
    const float* bias = (const float*)d_in[2];
    float* out = (float*)d_out;
    unsigned int* ws = (unsigned int*)d_ws;

    // pack weights into A-fragment layout (51200 B in d_ws)
    prep_weights_kernel<<<13, 256, 0, stream>>>(wgt, ws);

    dim3 grid(HO, DOUT, NB);
    dconv_kernel<<<grid, 256, 0, stream>>>(x, bias, (const bf16x8*)ws, out);
}

// Round 4
// 81.148 us; speedup vs baseline: 4.4753x; 1.1204x over previous
//
#include <hip/hip_runtime.h>
#include <hip/hip_bf16.h>

// DirectionalConv mode='down': out[b,co,d,h,w] =
//   sum_{ci,i,k} x[b,ci, d+i-2, h+i-2, w+k-2] * W[co,ci,i,0,k] + bias[co]
// x: (2,32,48,64,128) f32, W: (32,32,5,1,5), out: (2,32,48,68,128) f32.
//
// Diagonal-pair blocks: one block computes outputs (d0,h0) and (d0+1,h0+1),
// which share the staged diagonal planes (d0-2+j, h0-2+j), j=0..5.

#define NB   2
#define CIN  32
#define COUT 32
#define DD   48
#define HH   64
#define WW   128
#define DOUT 48
#define HO   68
#define WO   128

#define RS   192            // ushorts per col = 24 16B-chunks (6 planes * 4 octs)
#define NCOL 132            // col = w + 2; cols 0,1,130,131 always zero

typedef __attribute__((ext_vector_type(8))) short bf16x8;
typedef __attribute__((ext_vector_type(4))) float f32x4;

__device__ __forceinline__ unsigned short f32_to_bf16(float v) {
    unsigned int u; __builtin_memcpy(&u, &v, 4);
    u += 0x7FFFu + ((u >> 16) & 1u);        // RNE
    return (unsigned short)(u >> 16);
}
__device__ __forceinline__ unsigned int pk_bf16(float lo, float hi) {
    return (unsigned int)f32_to_bf16(lo) | ((unsigned int)f32_to_bf16(hi) << 16);
}

// LDS: logical (col, chunk t), t = j*4 + (ci>>3), j=plane 0..5.
// phys chunk = t ^ ((col>>1)&7)  (XOR flips low-3 bits only; t's 8-block kept).
// col stride 384 B == 0 mod 128 B, so banks depend only on swizzled chunk:
// both ds_write_b128 (cols 2*lane+{2,3}) and ds_read_b128 (cols wbase+lr+kk)
// hit the 8-rounds-per-wave floor (verified by lane arithmetic).
__device__ __forceinline__ int xs_chunk(int col, int t) {
    return col * RS + ((t ^ ((col >> 1) & 7)) << 3);
}

// Pre-pack weights into MFMA A-fragment order:
// frag f = (c*5 + kk)*2 + mt ; lane l ; 8 bf16 = W[mt*16+(l&15)][ci=(l>>4)*8+j][i=c][kk]
__global__ void prep_weights_kernel(const float* __restrict__ wgt,
                                    unsigned int* __restrict__ ws) {
    int s = blockIdx.x * 256 + threadIdx.x;     // 50 frags * 64 lanes = 3200 slots
    if (s >= 3200) return;
    int f = s >> 6, l = s & 63;
    int mt = f & 1, ckk = f >> 1;
    int c = ckk / 5, kk = ckk - c * 5;
    int co = mt * 16 + (l & 15);
    int cib = (l >> 4) * 8;
    unsigned int u[4];
#pragma unroll
    for (int jp = 0; jp < 4; ++jp) {
        float v0 = wgt[co * 800 + (cib + 2 * jp + 0) * 25 + c * 5 + kk];
        float v1 = wgt[co * 800 + (cib + 2 * jp + 1) * 25 + c * 5 + kk];
        u[jp] = (unsigned int)f32_to_bf16(v0) | ((unsigned int)f32_to_bf16(v1) << 16);
    }
    uint4 pack; pack.x = u[0]; pack.y = u[1]; pack.z = u[2]; pack.w = u[3];
    reinterpret_cast<uint4*>(ws)[s] = pack;
}

__global__ void __launch_bounds__(512, 4)
dconv_kernel(const float* __restrict__ x,
             const float* __restrict__ bias,
             const bf16x8* __restrict__ wsf,   // packed A fragments
             float* __restrict__ out) {
    __shared__ __align__(16) unsigned short xs[NCOL * RS];   // 50688 B

    const int tid  = threadIdx.x;
    const int lane = tid & 63;
    const int wv   = tid >> 6;          // 0..7

    // ---- diagonal-pair, XCD-chunked block remap ----
    // e = (b, dlt 0..68, t 0..23); pair = outputs (2t, hp) & (2t+1, hp+1),
    // hp = ((2t+dlt) % 69) - 1. Consecutive t within a dlt walk one diagonal
    // (shares 4/6 staged planes). 3312 = 8 XCDs * 414.
    int bid = blockIdx.x;
    int e   = (bid & 7) * 414 + (bid >> 3);
    int b   = (e >= 1656) ? 1 : 0;
    int r0  = e - b * 1656;
    int dlt = r0 / 24;
    int t   = r0 - dlt * 24;
    int hp  = (2 * t + dlt) % 69 - 1;   // -1..67
    const int d0 = 2 * t, h0 = hp;

    // ---- zero the 4 always-zero halo cols (0,1,130,131), all 24 chunks ----
    if (tid < 96) {
        int colIdx = tid / 24;              // 0..3
        int ch     = tid - colIdx * 24;     // 0..23
        int col    = (colIdx < 2) ? colIdx : 128 + colIdx;
        f32x4 z = {};
        *reinterpret_cast<f32x4*>(&xs[col * RS + ch * 8]) = z;
    }

    // ---- stage 6 diagonal planes, transposed, chunk-granular b128 writes ----
    // group g = j*4 + oct = chunk index; lane owns w-pair (2*lane, 2*lane+1).
    {
        const int w0   = lane * 2;
        const int col0 = w0 + 2, col1 = w0 + 3;
        const size_t plane = (size_t)DD * HH * WW;
        for (int g = wv; g < 24; g += 8) {          // 3 groups per wave
            int j = g >> 2, oct = g & 3;
            int dz = d0 + j - 2, hz = h0 + j - 2;
            float2 v[8];
#pragma unroll
            for (int k = 0; k < 8; ++k) { v[k].x = 0.f; v[k].y = 0.f; }
            if (((unsigned)dz < (unsigned)DD) && ((unsigned)hz < (unsigned)HH)) {
                const float* base = x + ((((size_t)b * CIN + oct * 8) * DD + dz) * HH + hz) * WW + w0;
#pragma unroll
                for (int k = 0; k < 8; ++k)
                    v[k] = *reinterpret_cast<const float2*>(base + (size_t)k * plane);
            }
            uint4 c0, c1;
            c0.x = pk_bf16(v[0].x, v[1].x); c0.y = pk_bf16(v[2].x, v[3].x);
            c0.z = pk_bf16(v[4].x, v[5].x); c0.w = pk_bf16(v[6].x, v[7].x);
            c1.x = pk_bf16(v[0].y, v[1].y); c1.y = pk_bf16(v[2].y, v[3].y);
            c1.z = pk_bf16(v[4].y, v[5].y); c1.w = pk_bf16(v[6].y, v[7].y);
            *reinterpret_cast<uint4*>(&xs[xs_chunk(col0, g)]) = c0;
            *reinterpret_cast<uint4*>(&xs[xs_chunk(col1, g)]) = c1;
        }
    }
    __syncthreads();

    // ---- MFMA: wave wv owns w-tile [wv*16, wv*16+16), both outputs ----
    const int lr = lane & 15;
    const int lg = lane >> 4;
    const int wbase = wv * 16;

    f32x4 acc[2][2] = {};   // [mt][out]

#pragma unroll
    for (int kk = 0; kk < 5; ++kk) {
        bf16x8 a[5][2];
#pragma unroll
        for (int c = 0; c < 5; ++c) {
            int f0 = ((c * 5 + kk) * 2) * 64 + lane;
            a[c][0] = wsf[f0];
            a[c][1] = wsf[f0 + 64];
        }
        const int col = wbase + lr + kk;            // <= 112+15+4 = 131
#pragma unroll
        for (int j = 0; j < 6; ++j) {
            bf16x8 bv = *reinterpret_cast<const bf16x8*>(&xs[xs_chunk(col, j * 4 + lg)]);
            if (j < 5) {    // output0 (d0,h0): tap c=j
                acc[0][0] = __builtin_amdgcn_mfma_f32_16x16x32_bf16(a[j][0], bv, acc[0][0], 0, 0, 0);
                acc[1][0] = __builtin_amdgcn_mfma_f32_16x16x32_bf16(a[j][1], bv, acc[1][0], 0, 0, 0);
            }
            if (j > 0) {    // output1 (d0+1,h0+1): tap c=j-1
                acc[0][1] = __builtin_amdgcn_mfma_f32_16x16x32_bf16(a[j - 1][0], bv, acc[0][1], 0, 0, 0);
                acc[1][1] = __builtin_amdgcn_mfma_f32_16x16x32_bf16(a[j - 1][1], bv, acc[1][1], 0, 0, 0);
            }
        }
    }

    // ---- epilogue: D col=lane&15 (w), row=(lane>>4)*4+reg (co) ----
    const bool v0 = (h0 >= 0);
    const bool v1 = (h0 + 1 <= HO - 1);
    const int w = wbase + lr;
#pragma unroll
    for (int mt = 0; mt < 2; ++mt) {
#pragma unroll
        for (int rg = 0; rg < 4; ++rg) {
            int co = mt * 16 + lg * 4 + rg;
            float bs = bias[co];
            size_t base = (((size_t)b * COUT + co) * DOUT);
            if (v0) out[((base + d0) * HO + h0) * WO + w]           = acc[mt][0][rg] + bs;
            if (v1) out[((base + d0 + 1) * HO + h0 + 1) * WO + w]   = acc[mt][1][rg] + bs;
        }
    }
}

extern "C" void kernel_launch(void* const* d_in, const int* in_sizes, int n_in,
                              void* d_out, int out_size, void* d_ws, size_t ws_size,
                              hipStream_t stream) {
    const float* x    = (const float*)d_in[0];
    const float* wgt  = (const float*)d_in[1];
    const float* bias = (const float*)d_in[2];
    float* out = (float*)d_out;
    unsigned int* ws = (unsigned int*)d_ws;

    // pack weights into A-fragment layout (51200 B in d_ws)
    prep_weights_kernel<<<13, 256, 0, stream>>>(wgt, ws);

    dconv_kernel<<<3312, 512, 0, stream>>>(x, bias, (const bf16x8*)ws, out);
}

// Round 5
// 66.213 us; speedup vs baseline: 5.4848x; 1.2256x over previous
//
#include <hip/hip_runtime.h>
#include <hip/hip_bf16.h>

// DirectionalConv mode='down': out[b,co,d,h,w] =
//   sum_{ci,i,k} x[b,ci, d+i-2, h+i-2, w+k-2] * W[co,ci,i,0,k] + bias[co]
// x: (2,32,48,64,128) f32, W: (32,32,5,1,5), out: (2,32,48,68,128) f32.
//
// Quad-diagonal blocks: one block computes outputs (d0+q, h0+q), q=0..3,
// sharing 8 staged diagonal planes (d0-2+j, h0-2+j), j=0..7.

#define NB   2
#define CIN  32
#define COUT 32
#define DD   48
#define HH   64
#define WW   128
#define DOUT 48
#define HO   68
#define WO   128

#define RS   256            // ushorts per col = 32 16B-chunks (8 planes * 4 octs)
#define NCOL 132            // col = w + 2; cols 0,1,130,131 always zero

typedef __attribute__((ext_vector_type(8))) short bf16x8;
typedef __attribute__((ext_vector_type(4))) float f32x4;

__device__ __forceinline__ unsigned short f32_to_bf16(float v) {
    unsigned int u; __builtin_memcpy(&u, &v, 4);
    u += 0x7FFFu + ((u >> 16) & 1u);        // RNE
    return (unsigned short)(u >> 16);
}
// packed pair conversion -> v_cvt_pk_bf16_f32 (1 instr for 2 floats)
__device__ __forceinline__ unsigned int pk2(float a, float b) {
    float2 t; t.x = a; t.y = b;
    __hip_bfloat162 r = __float22bfloat162_rn(t);
    unsigned int u; __builtin_memcpy(&u, &r, 4);
    return u;
}

// LDS: logical (col, chunk t), t = j*4 + oct (oct = ci>>3), j = plane 0..7.
// phys chunk = t ^ s, s = (col>>1)&7. col stride 512 B == 0 mod 128 B, so
// banks depend only on swizzled chunk; writes (cols 2*lane+{2,3}) and reads
// (cols wbase+lr+kk) both land at the 8-rounds-per-wave floor.
__device__ __forceinline__ int xs_chunk(int col, int t) {
    return col * RS + ((t ^ ((col >> 1) & 7)) << 3);
}

// Pre-pack weights into MFMA A-fragment order:
// frag f = (c*5 + kk)*2 + mt ; lane l ; 8 bf16 = W[mt*16+(l&15)][ci=(l>>4)*8+j][i=c][kk]
__global__ void prep_weights_kernel(const float* __restrict__ wgt,
                                    unsigned int* __restrict__ ws) {
    int s = blockIdx.x * 256 + threadIdx.x;     // 50 frags * 64 lanes = 3200 slots
    if (s >= 3200) return;
    int f = s >> 6, l = s & 63;
    int mt = f & 1, ckk = f >> 1;
    int c = ckk / 5, kk = ckk - c * 5;
    int co = mt * 16 + (l & 15);
    int cib = (l >> 4) * 8;
    unsigned int u[4];
#pragma unroll
    for (int jp = 0; jp < 4; ++jp) {
        float v0 = wgt[co * 800 + (cib + 2 * jp + 0) * 25 + c * 5 + kk];
        float v1 = wgt[co * 800 + (cib + 2 * jp + 1) * 25 + c * 5 + kk];
        u[jp] = (unsigned int)f32_to_bf16(v0) | ((unsigned int)f32_to_bf16(v1) << 16);
    }
    uint4 pack; pack.x = u[0]; pack.y = u[1]; pack.z = u[2]; pack.w = u[3];
    reinterpret_cast<uint4*>(ws)[s] = pack;
}

__global__ void __launch_bounds__(512, 4)
dconv_kernel(const float* __restrict__ x,
             const float* __restrict__ bias,
             const bf16x8* __restrict__ wsf,   // packed A fragments
             float* __restrict__ out) {
    __shared__ __align__(16) unsigned short xs[NCOL * RS];   // 67584 B

    const int tid  = threadIdx.x;
    const int lane = tid & 63;
    const int wv   = tid >> 6;          // 0..7

    // ---- quad-diagonal, XCD-chunked block remap ----
    // e = (b, dlt 0..70, qq 0..11): d0 = 4*qq, h0 = ((d0+dlt)%71)-3.
    // Outputs (d0+q, h0+q) masked to 0<=h<=67; each valid (d,h) covered once.
    // Consecutive e walk one diagonal (quads share 4/8 planes). 1704 = 8*213.
    int bid = blockIdx.x;
    int e   = (bid & 7) * 213 + (bid >> 3);
    int b   = (e >= 852) ? 1 : 0;
    int r0  = e - b * 852;
    int dlt = r0 / 12;
    int qq  = r0 - dlt * 12;
    const int d0 = 4 * qq;
    const int h0 = (d0 + dlt) % 71 - 3;     // -3..67

    // ---- zero the 4 always-zero halo cols (0,1,130,131), all 32 chunks ----
    if (tid < 128) {
        int colIdx = tid >> 5;              // 0..3
        int ch     = tid & 31;              // 0..31
        int col    = (colIdx < 2) ? colIdx : 128 + colIdx;
        f32x4 z = {};
        *reinterpret_cast<f32x4*>(&xs[col * RS + ch * 8]) = z;
    }

    // ---- stage 8 diagonal planes, transposed, chunk-granular b128 writes ----
    // group g = j*4 + oct = chunk index; lane owns w-pair (2*lane, 2*lane+1).
    {
        const int w0   = lane * 2;
        const int col0 = w0 + 2, col1 = w0 + 3;
        const size_t plane = (size_t)DD * HH * WW;
        for (int g = wv; g < 32; g += 8) {          // 4 groups per wave
            int j = g >> 2, oct = g & 3;
            int dz = d0 + j - 2, hz = h0 + j - 2;
            float2 v[8];
#pragma unroll
            for (int k = 0; k < 8; ++k) { v[k].x = 0.f; v[k].y = 0.f; }
            if (((unsigned)dz < (unsigned)DD) && ((unsigned)hz < (unsigned)HH)) {
                const float* base = x + ((((size_t)b * CIN + oct * 8) * DD + dz) * HH + hz) * WW + w0;
#pragma unroll
                for (int k = 0; k < 8; ++k)
                    v[k] = *reinterpret_cast<const float2*>(base + (size_t)k * plane);
            }
            uint4 c0, c1;
            c0.x = pk2(v[0].x, v[1].x); c0.y = pk2(v[2].x, v[3].x);
            c0.z = pk2(v[4].x, v[5].x); c0.w = pk2(v[6].x, v[7].x);
            c1.x = pk2(v[0].y, v[1].y); c1.y = pk2(v[2].y, v[3].y);
            c1.z = pk2(v[4].y, v[5].y); c1.w = pk2(v[6].y, v[7].y);
            *reinterpret_cast<uint4*>(&xs[xs_chunk(col0, g)]) = c0;
            *reinterpret_cast<uint4*>(&xs[xs_chunk(col1, g)]) = c1;
        }
    }
    __syncthreads();

    // ---- MFMA: wave wv owns w-tile [wv*16, wv*16+16), all 4 outputs ----
    const int lr = lane & 15;
    const int lg = lane >> 4;
    const int wbase = wv * 16;

    f32x4 acc[2][4] = {};   // [mt][q]

#pragma unroll 1
    for (int kk = 0; kk < 5; ++kk) {
        bf16x8 a[5][2];
#pragma unroll
        for (int c = 0; c < 5; ++c) {
            int f0 = ((c * 5 + kk) * 2) * 64 + lane;
            a[c][0] = wsf[f0];
            a[c][1] = wsf[f0 + 64];
        }
        // hoisted swizzle decomposition: chunk(j, lg) ^ s =
        //   (j>>1)*8 + ((j&1)^sb)*4 + (lg^(s&3)); reads become imm offsets.
        const int col = wbase + lr + kk;            // <= 112+15+4 = 131
        const int s   = (col >> 1) & 7;
        const int sb  = s >> 2;
        const int lg2 = lg ^ (s & 3);
        const unsigned short* pE = &xs[col * RS + ((sb * 4 + lg2) << 3)];
        const unsigned short* pO = &xs[col * RS + ((((sb ^ 1) << 2) + lg2) << 3)];
#pragma unroll
        for (int j = 0; j < 8; ++j) {
            const unsigned short* p = (j & 1) ? pO : pE;
            bf16x8 bv = *reinterpret_cast<const bf16x8*>(p + (j >> 1) * 64);
            const int qlo = (j > 4) ? (j - 4) : 0;
            const int qhi = (j < 3) ? j : 3;
#pragma unroll
            for (int q = qlo; q <= qhi; ++q) {
                const int c = j - q;                // tap for output q at plane j
                acc[0][q] = __builtin_amdgcn_mfma_f32_16x16x32_bf16(a[c][0], bv, acc[0][q], 0, 0, 0);
                acc[1][q] = __builtin_amdgcn_mfma_f32_16x16x32_bf16(a[c][1], bv, acc[1][q], 0, 0, 0);
            }
        }
    }

    // ---- epilogue: D col=lane&15 (w), row=(lane>>4)*4+reg (co) ----
    const int w = wbase + lr;
#pragma unroll
    for (int q = 0; q < 4; ++q) {
        const int hq = h0 + q;
        if (hq < 0 || hq >= HO) continue;
        const int dq = d0 + q;
#pragma unroll
        for (int mt = 0; mt < 2; ++mt) {
#pragma unroll
            for (int rg = 0; rg < 4; ++rg) {
                int co = mt * 16 + lg * 4 + rg;
                out[((((size_t)b * COUT + co) * DOUT + dq) * HO + hq) * WO + w] =
                    acc[mt][q][rg] + bias[co];
            }
        }
    }
}

extern "C" void kernel_launch(void* const* d_in, const int* in_sizes, int n_in,
                              void* d_out, int out_size, void* d_ws, size_t ws_size,
                              hipStream_t stream) {
    const float* x    = (const float*)d_in[0];
    const float* wgt  = (const float*)d_in[1];
    const float* bias = (const float*)d_in[2];
    float* out = (float*)d_out;
    unsigned int* ws = (unsigned int*)d_ws;

    // pack weights into A-fragment layout (51200 B in d_ws)
    prep_weights_kernel<<<13, 256, 0, stream>>>(wgt, ws);

    dconv_kernel<<<1704, 512, 0, stream>>>(x, bias, (const bf16x8*)ws, out);
}